// Round 11
// baseline (403.790 us; speedup 1.0000x reference)
//
#include <hip/hip_runtime.h>
#include <stdint.h>

// ---------------------------------------------------------------------------
// KAN block: out = kan(kan(x)).  Each layer = GEMM with K split in 2 segments:
//   seg 0: silu(x)       (K0 = in)    vs w_base   (out x in)
//   seg 1: bspline bases (K1 = in*8)  vs w_spline (out x in*8, contiguous)
// Input dtype (f32 vs bf16) detected at runtime from grid[0] = -2.2.
// R3: split-K GEMMs into f32 atomics (occupancy 11%->50%).
// R4: act divides -> 3 reciprocals (uniform grid), 4 elems/thread.
// R5: XOR-swizzled LDS (conflicts 4.25e7 -> 0), 128x128 tiles.
// R6: double-buffered LDS at 128x128 (64KB -> 2 blocks/CU) REGRESSED.
// R7: L1 unsplit -> bf16 H.   R8: XCD swizzle (FETCH 318->170MB, Mfma 23->27).
// R9: gemm1 split-K=2 disjoint: NO CHANGE at 128x128 -> inner loop plateau.
// R10: fuse act2 INTO gemm1's epilogue (OUT_MODE=3): kills act2 + H trip.
// R11: gemm1 BM 128->64: 512->1024 blocks, 316->183us.
// R12: 64x64 gemm1 REGRESSED — but VGPR was 68-84 (above the 64-VGPR
//      occupancy cliff), so the 2048-block grid still got only 4 blocks/CU
//      and the halved MFMA:staging ratio was a pure loss.  [confounded]
// R13-R17: recompute arc (BS2 eliminated) net REGRESSED (480us). Reverted.
//      KEPT fast_bases8 (numerics verified, absmax unchanged R16-R18).
// R18: fast_bases8 in gemm1 epilogue + act1: gemm1 183->147us, VGPR 84->48,
//      total 402->390us. WIN — best so far.
// R19: 2-phase dbuf gemm1 REGRESSED (147->211us): 48KB LDS cost occupancy.
//      Occupancy > schedule engineering on this kernel (R6/m99 lesson).
// R20: gemm2 64x256 (half A-re-fetch): 397us, ~7us WORSE -> gemm2 not
//      fetch-bound. Reverted to 128x128.
// R21: retry R12's gemm1 64x64 with the VGPR confound removed by R18:
//      VGPR ~40 (<64 cliff) + LDS 16KB -> grid (32,64)=2048 blocks can now
//      actually sit 8 blocks/CU (32 waves/CU, 2x today). Trades MFMA:staging
//      ratio (8:4 vs 16:6) for doubled TLP — the resource this kernel has
//      been starved of all session (R11: +73% from 2->4 blocks/CU).
// ---------------------------------------------------------------------------

typedef __bf16 bf16x8_t __attribute__((ext_vector_type(8)));
typedef float f32x4_t __attribute__((ext_vector_type(4)));

__device__ __forceinline__ float bf2f(unsigned short u) {
    union { float f; uint32_t i; } c; c.i = ((uint32_t)u) << 16; return c.f;
}
__device__ __forceinline__ unsigned short f2bf(float f) {
    union { float f; uint32_t u; } c; c.f = f;
    uint32_t u = c.u;
    u += 0x7FFFu + ((u >> 16) & 1u);   // round-to-nearest-even
    return (unsigned short)(u >> 16);
}
__device__ __forceinline__ bool f32world(const void* gridp) {
    return ((*(const unsigned int*)gridp) & 0xFFFFu) == 0xCCCDu;
}

// load knots (world-dependent) + uniform-grid inverse denominators
__device__ __forceinline__ void load_knots(const void* gridp, float* t, float* rr) {
    if (f32world(gridp)) {
        const float* g = (const float*)gridp;
#pragma unroll
        for (int k = 0; k < 12; ++k) t[k] = g[k];
    } else {
        const unsigned short* g = (const unsigned short*)gridp;
#pragma unroll
        for (int k = 0; k < 12; ++k) t[k] = bf2f(g[k]);
    }
    rr[0] = 1.0f / (t[1] - t[0]);
    rr[1] = 1.0f / (t[2] - t[0]);
    rr[2] = 1.0f / (t[3] - t[0]);
}

// Fast uniform-grid bases: only 4 of 8 cubic bases are nonzero at any x.
// span i = floor((x-t0)/h) (valid 0..10), u = frac; basis j nonzero iff
// d = i-j in {0..3} with the standard uniform cubic polys.  C2-continuous
// at span edges; i outside [0,10] -> all zero.  ~90 lane-ops vs ~240 for
// Cox-de-Boor.  Numerically verified R16-R20 (absmax unchanged). [R16/R18]
__device__ __forceinline__ int4 fast_bases8(float x, float t0, float invh) {
    float y  = (x - t0) * invh;
    float fi = floorf(y);
    int   i  = (int)fi;
    float u  = y - fi;
    float u2 = u * u, u3 = u2 * u;
    float um = 1.0f - u;
    const float c6 = 1.0f / 6.0f;
    float p0 = u3 * c6;                                  // d=0 (j=i)
    float p1 = (-3.f*u3 + 3.f*u2 + 3.f*u + 1.f) * c6;    // d=1
    float p2 = (3.f*u3 - 6.f*u2 + 4.f) * c6;             // d=2
    float p3 = um * um * um * c6;                        // d=3 (j=i-3)
    bool valid = (i >= 0) && (i <= 10);
    union { int4 v; unsigned short h[8]; } r;
#pragma unroll
    for (int g = 0; g < 8; ++g) {
        int d = i - g;
        float val = (d == 0) ? p0 : (d == 1) ? p1 : (d == 2) ? p2
                  : (d == 3) ? p3 : 0.0f;
        r.h[g] = f2bf(valid ? val : 0.0f);
    }
    return r.v;
}

// --------------------- merged weight f32->bf16 (or copy) -------------------
__global__ __launch_bounds__(256)
void cvt4_kernel(const void* __restrict__ s0, const void* __restrict__ s1,
                 const void* __restrict__ s2, const void* __restrict__ s3,
                 unsigned short* __restrict__ dst, const void* __restrict__ gridp)
{
    const int n0 = 262144;            // 2048*512/4
    const int n01 = n0 + 2097152;     // + 2048*512*8/4
    const int n012 = n01 + 262144;    // + 512*2048/4
    const int n = n012 + 2097152;     // + 512*2048*8/4
    int i = blockIdx.x * 256 + threadIdx.x;
    if (i >= n) return;
    const void* src; long off;
    if      (i < n0)   { src = s0; off = i; }
    else if (i < n01)  { src = s1; off = i - n0; }
    else if (i < n012) { src = s2; off = i - n01; }
    else               { src = s3; off = i - n012; }
    if (f32world(gridp)) {
        float4 v = ((const float4*)src)[off];
        ushort4 o;
        o.x = f2bf(v.x); o.y = f2bf(v.y); o.z = f2bf(v.z); o.w = f2bf(v.w);
        ((ushort4*)dst)[i] = o;
    } else {
        ((ushort4*)dst)[i] = ((const ushort4*)src)[off];
    }
}

// --------------------------- activations: silu + 8 bases -------------------
// XMODE: 0 = raw input (world f32/bf16), 1 = ws bf16.
// zbuf!=null: also zero zn4 float4s (folds the C2 memset into this dispatch).
template<int XMODE>
__global__ __launch_bounds__(256)
void act_kernel(const void* __restrict__ Xv, const void* __restrict__ gridp,
                unsigned short* __restrict__ S, unsigned short* __restrict__ BS,
                int total4, float* __restrict__ zbuf, int zn4)
{
    int gi = blockIdx.x * 256 + threadIdx.x;
    if (gi >= total4) return;

    if (zbuf && gi < zn4) ((float4*)zbuf)[gi] = (float4){0.f, 0.f, 0.f, 0.f};

    const bool w32 = f32world(gridp);
    float t[12], rr[3];
    load_knots(gridp, t, rr);

    float xv[4];
    if (XMODE == 0 && w32) {
        float4 v = ((const float4*)Xv)[gi];
        xv[0] = v.x; xv[1] = v.y; xv[2] = v.z; xv[3] = v.w;
    } else {
        ushort4 v = ((const ushort4*)Xv)[gi];
        xv[0] = bf2f(v.x); xv[1] = bf2f(v.y); xv[2] = bf2f(v.z); xv[3] = bf2f(v.w);
    }

    ushort4 sOut;
    unsigned short* sp = (unsigned short*)&sOut;
    int4 bsOut[4];

#pragma unroll
    for (int e = 0; e < 4; ++e) {
        float x = xv[e];
        float sg = 1.0f / (1.0f + __expf(-x));
        sp[e] = f2bf(x * sg);
        bsOut[e] = fast_bases8(x, t[0], rr[0]);           // [R18]
    }

    ((ushort4*)S)[gi] = sOut;
    int4* bp = (int4*)&BS[(long)gi * 32];
#pragma unroll
    for (int e = 0; e < 4; ++e) bp[e] = bsOut[e];
}

// --------------------------- two-segment MFMA bf16 GEMM --------------------
// Single-buffered LDS (R5/R19-confirmed winner). XOR-swizzled (0 conflicts).
// XCD-aware tile swizzle (R8). blockIdx.z selects K-tile range [kt0,kt1).
// OUT_MODE: 1 = f32 atomicAdd (split-K), 2 = final world-dependent store,
//           3 = fused layer-boundary epilogue (silu + fast_bases8). [R10/R18]
template<int BM, int BN, int OUT_MODE>
__global__ __launch_bounds__(256)
void gemm_seg(const unsigned short* __restrict__ A0, int K0,
              const unsigned short* __restrict__ A1, int K1,
              const unsigned short* __restrict__ B0,
              const unsigned short* __restrict__ B1,
              void* __restrict__ Cv, unsigned short* __restrict__ BSp,
              int N, int crow0, int ktiles,
              const void* __restrict__ gridp)
{
    constexpr int BK = 64;
    constexpr int TM = BM / 32;
    constexpr int TN = BN / 32;

    __shared__ unsigned short As[BM * BK];
    __shared__ unsigned short Bs[BN * BK];

    const int tid  = threadIdx.x;
    const int lane = tid & 63;
    const int w    = tid >> 6;
    const int wm   = w & 1;
    const int wn   = w >> 1;

    // ---- XCD-aware tile swizzle ----
    const int gx = gridDim.x, gy = gridDim.y, gz = gridDim.z;
    int bx = blockIdx.x, by = blockIdx.y, bz = blockIdx.z;
    {
        int NB = gx * gy * gz;
        if ((NB & 7) == 0) {
            int F = bx + gx * (by + gy * bz);      // launch order (x fastest)
            int T = (F & 7) * (NB >> 3) + (F >> 3); // XCD gets contiguous band
            int pl = gx * gy;
            bz = T / pl;
            int r = T - bz * pl;
            by = r / gx;
            bx = r - by * gx;
        }
    }

    const int rowA0 = by * BM;
    const int colC0 = bx * BN;

    const int nkt0 = K0 / BK;
    const int nkt  = nkt0 + K1 / BK;
    const int kt0  = bz * ktiles;
    const int kt1  = (kt0 + ktiles < nkt) ? kt0 + ktiles : nkt;

    // staging: lane covers (row = (w<<3)+(lane>>3), LDS slot = lane&7);
    // fetch global chunk (slot ^ (row&7)) so readers can de-swizzle.
    const int srow = (w << 3) + (lane >> 3);
    const int scol = (((lane & 7) ^ ((lane >> 3) & 7)) << 3);   // elements

    // fragment-read swizzled chunk offsets (elements), per ks
    const int q  = lane >> 4;       // 0..3
    const int l7 = lane & 7;        // == (fragment row) & 7
    const int cidx0 = ((q) ^ l7) << 3;
    const int cidx1 = ((4 + q) ^ l7) << 3;

    f32x4_t acc[TM][TN];
#pragma unroll
    for (int i = 0; i < TM; ++i)
#pragma unroll
        for (int j = 0; j < TN; ++j)
            acc[i][j] = (f32x4_t){0.f, 0.f, 0.f, 0.f};

    for (int kt = kt0; kt < kt1; ++kt) {
        const unsigned short* Abase;
        const unsigned short* Bbase;
        long ld; int ko;
        if (kt < nkt0) { Abase = A0; Bbase = B0; ld = K0; ko = kt * BK; }
        else           { Abase = A1; Bbase = B1; ld = K1; ko = (kt - nkt0) * BK; }

#pragma unroll
        for (int i = 0; i < BM / 32; ++i) {
            const unsigned short* g = Abase + (long)(rowA0 + i * 32 + srow) * ld + ko + scol;
            __builtin_amdgcn_global_load_lds(
                (const __attribute__((address_space(1))) void*)g,
                (__attribute__((address_space(3))) void*)&As[(i * 32 + (w << 3)) * BK],
                16, 0, 0);
        }
#pragma unroll
        for (int i = 0; i < BN / 32; ++i) {
            const unsigned short* g = Bbase + (long)(colC0 + i * 32 + srow) * ld + ko + scol;
            __builtin_amdgcn_global_load_lds(
                (const __attribute__((address_space(1))) void*)g,
                (__attribute__((address_space(3))) void*)&Bs[(i * 32 + (w << 3)) * BK],
                16, 0, 0);
        }
        __syncthreads();

#pragma unroll
        for (int ks = 0; ks < 2; ++ks) {
            const int cidx = ks ? cidx1 : cidx0;
            bf16x8_t af[TM], bfr[TN];
#pragma unroll
            for (int tm = 0; tm < TM; ++tm)
                af[tm] = *(const bf16x8_t*)&As[(wm * (BM / 2) + tm * 16 + (lane & 15)) * BK
                                               + cidx];
#pragma unroll
            for (int tn = 0; tn < TN; ++tn)
                bfr[tn] = *(const bf16x8_t*)&Bs[(wn * (BN / 2) + tn * 16 + (lane & 15)) * BK
                                                + cidx];
#pragma unroll
            for (int tm = 0; tm < TM; ++tm)
#pragma unroll
                for (int tn = 0; tn < TN; ++tn)
                    acc[tm][tn] = __builtin_amdgcn_mfma_f32_16x16x32_bf16(
                        af[tm], bfr[tn], acc[tm][tn], 0, 0, 0);
        }
        __syncthreads();
    }

    // C/D layout: col = lane&15, row = (lane>>4)*4 + reg  [m89-verified]
    const bool w32 = (OUT_MODE == 2) ? f32world(gridp) : false;
    float t[12], rr[3];
    if (OUT_MODE == 3) load_knots(gridp, t, rr);

#pragma unroll
    for (int tm = 0; tm < TM; ++tm) {
#pragma unroll
        for (int tn = 0; tn < TN; ++tn) {
            int row0 = crow0 + rowA0 + wm * (BM / 2) + tm * 16 + (lane >> 4) * 4;
            int col  = colC0 + wn * (BN / 2) + tn * 16 + (lane & 15);
#pragma unroll
            for (int r = 0; r < 4; ++r) {
                long off = (long)(row0 + r) * N + col;
                float v = acc[tm][tn][r];
                if (OUT_MODE == 1) {
                    unsafeAtomicAdd(&((float*)Cv)[off], v);
                } else if (OUT_MODE == 3) {
                    float sg = 1.0f / (1.0f + __expf(-v));
                    ((unsigned short*)Cv)[off] = f2bf(v * sg);
                    *(int4*)&BSp[off * 8] = fast_bases8(v, t[0], rr[0]);  // [R18]
                } else if (w32) {
                    ((float*)Cv)[off] = v;
                } else {
                    ((unsigned short*)Cv)[off] = f2bf(v);
                }
            }
        }
    }
}

// ------------------- f32 accumulator -> final output -----------------------
__global__ __launch_bounds__(256)
void accum_to_out(const float* __restrict__ acc, void* __restrict__ out,
                  int n4, const void* __restrict__ gridp)
{
    int i = blockIdx.x * 256 + threadIdx.x;
    if (i >= n4) return;
    float4 v = ((const float4*)acc)[i];
    if (f32world(gridp)) {
        ((float4*)out)[i] = v;
    } else {
        ushort4 o;
        o.x = f2bf(v.x); o.y = f2bf(v.y); o.z = f2bf(v.z); o.w = f2bf(v.w);
        ((ushort4*)out)[i] = o;
    }
}

// --------------------------- launcher --------------------------------------
extern "C" void kernel_launch(void* const* d_in, const int* in_sizes, int n_in,
                              void* d_out, int out_size, void* d_ws, size_t ws_size,
                              hipStream_t stream)
{
    const void* x   = d_in[0];
    const void* grd = d_in[1];
    const void* w1b = d_in[2];
    const void* w1s = d_in[3];
    const void* w2b = d_in[4];
    const void* w2s = d_in[5];

    const int NTOK = 4096, D1 = 512, D2 = 2048;
    const size_t MiB = 1024 * 1024;
    char* ws = (char*)d_ws;

    if (ws_size >= 224 * MiB) {
        // ------------------- fused path (R10/R18/R21) -------------------
        unsigned short* wcat   = (unsigned short*)ws;              // 36 MiB total
        unsigned short* w1b_bf = (unsigned short*)(ws);            //  2 MiB
        unsigned short* w1s_bf = (unsigned short*)(ws + 2  * MiB); // 16 MiB
        unsigned short* w2b_bf = (unsigned short*)(ws + 18 * MiB); //  2 MiB
        unsigned short* w2s_bf = (unsigned short*)(ws + 20 * MiB); // 16 MiB
        unsigned short* S1     = (unsigned short*)(ws + 36 * MiB); //  4 MiB
        unsigned short* BS1    = (unsigned short*)(ws + 40 * MiB); // 32 MiB
        unsigned short* S2     = (unsigned short*)(ws + 72 * MiB); // 16 MiB bf16 4096x2048
        unsigned short* BS2    = (unsigned short*)(ws + 88 * MiB); // 128 MiB (ends 216)
        float*          C2     = (float*)(ws + 216 * MiB);         //  8 MiB (ends 224)

        cvt4_kernel<<<(4718592 + 255) / 256, 256, 0, stream>>>(w1b, w1s, w2b, w2s, wcat, grd);

        // act1 (+ zero C2 for gemm2's atomics)
        act_kernel<0><<<(NTOK * D1 / 4 + 255) / 256, 256, 0, stream>>>(
            x, grd, S1, BS1, NTOK * D1 / 4, (float*)C2, NTOK * D1 / 4);

        // gemm1: R21 64x64 tiles -> grid (32,64)=2048 blocks; with R18's
        // VGPR<=48 (below the 64-VGPR cliff) + LDS 16KB this can sit
        // 8 blocks/CU = 32 waves/CU (2x R18's residency).
        {
            dim3 g(D2 / 64, NTOK / 64, 1);
            gemm_seg<64, 64, 3><<<g, 256, 0, stream>>>(
                S1, D1, BS1, D1 * 8, w1b_bf, w1s_bf,
                (void*)S2, BS2, D2, 0, 72, grd);
        }

        // gemm2: split-K=8 atomics, 128x128 (R20 confirmed best), 1024 blocks
        {
            dim3 g(D1 / 128, NTOK / 128, 8);
            gemm_seg<128, 128, 1><<<g, 256, 0, stream>>>(
                S2, D2, BS2, D2 * 8, w2b_bf, w2s_bf,
                (void*)C2, nullptr, D1, 0, 36, grd);
        }

        accum_to_out<<<(NTOK * D1 / 4 + 255) / 256, 256, 0, stream>>>(
            C2, d_out, NTOK * D1 / 4, grd);
    } else {
        // ------------------- legacy small-ws path -------------------
        unsigned short* w1b_bf = (unsigned short*)(ws);
        unsigned short* w1s_bf = (unsigned short*)(ws + 2  * MiB);
        unsigned short* w2b_bf = (unsigned short*)(ws + 18 * MiB);
        unsigned short* w2s_bf = (unsigned short*)(ws + 20 * MiB);
        unsigned short* H      = (unsigned short*)(ws + 36 * MiB);
        unsigned short* S1     = (unsigned short*)(ws + 52 * MiB);
        unsigned short* BS1    = (unsigned short*)(ws + 56 * MiB);
        unsigned short* S2     = (unsigned short*)(ws + 52 * MiB);
        unsigned short* BS2    = (unsigned short*)(ws + 68 * MiB);

        int CT;
        if      (ws_size >= 100 * MiB) CT = 1024;
        else                           CT = 256;

        cvt4_kernel<<<(4718592 + 255) / 256, 256, 0, stream>>>(
            w1b, w1s, w2b, w2s, (unsigned short*)ws, grd);

        {
            act_kernel<0><<<(NTOK * D1 / 4 + 255) / 256, 256, 0, stream>>>(
                x, grd, S1, BS1, NTOK * D1 / 4, nullptr, 0);
            dim3 g(D2 / 128, NTOK / 128, 1);
            gemm_seg<128, 128, 2><<<g, 256, 0, stream>>>(
                S1, D1, BS1, D1 * 8, w1b_bf, w1s_bf, (void*)H, nullptr,
                D2, 0, 72, grd);
        }
        int nch = NTOK / CT;
        for (int c = 0; c < nch; ++c) {
            long tokOff = (long)c * CT;
            act_kernel<1><<<(CT * D2 / 4 + 255) / 256, 256, 0, stream>>>(
                (const void*)(H + tokOff * D2), grd, S2 + tokOff * D2, BS2,
                CT * D2 / 4, nullptr, 0);
            dim3 g(D1 / 128, CT / 64, 1);
            gemm_seg<64, 128, 2><<<g, 256, 0, stream>>>(
                S2 + tokOff * D2, D2, BS2, D2 * 8, w2b_bf, w2s_bf,
                d_out, nullptr, D1, (int)tokOff, 288, grd);
        }
    }
}

// Round 12
// 386.140 us; speedup vs baseline: 1.0457x; 1.0457x over previous
//
#include <hip/hip_runtime.h>
#include <stdint.h>

// ---------------------------------------------------------------------------
// KAN block: out = kan(kan(x)).  Each layer = GEMM with K split in 2 segments:
//   seg 0: silu(x)       (K0 = in)    vs w_base   (out x in)
//   seg 1: bspline bases (K1 = in*8)  vs w_spline (out x in*8, contiguous)
// Input dtype (f32 vs bf16) detected at runtime from grid[0] = -2.2.
// R3: split-K GEMMs into f32 atomics.  R4: act reciprocals.
// R5: XOR-swizzled LDS (0 conflicts), 128x128 tiles.
// R6/R19: double-buffered LDS REGRESSED both times (LDS kills occupancy;
//      implicit wave-overlap at 4 blocks/CU beats explicit pipelining).
// R7: bf16 H.  R8: XCD swizzle.  R9: split-K=2 gemm1 null.
// R10: fused act2 epilogue (OUT_MODE=3).  R11: gemm1 64x128: 316->183us.
// R12: 64x64 confounded regression.  R13-R17: recompute arc REGRESSED
//      (VALU-bound -> latency-bound plateau 259us); KEPT fast_bases8.
// R18: fast_bases8 in epilogue+act1: gemm1 147us, VGPR 48. 390us BEST.
// R20: gemm2 64x256 null (+7us) -> gemm2 not fetch-bound.
// R21: gemm1 64x64: occupancy 37->64% as predicted BUT FETCH 137->352MB
//      (BN halved -> B-panel re-reads doubled; 39% HBM) -> 165us. Tile
//      space for gemm1 now fully measured: 64x128@4blk/CU is optimal.
// R22: (a) merge cvt4+act1 into ONE dispatch (independent streams,
//      currently serialized; overlap + one less launch gap);
//      (b) gemm2 128x128 -> 64x128 split-K=8: grid (4,64,8)=2048 blocks,
//      LDS 24KB -> 6 blocks/CU (+50% residency). Unlike R21: BN stays 128
//      so A-re-fetch stays x4 (no fetch explosion); MFMA:staging ratio
//      16:6 = the proven gemm1 shape. R12 couldn't see this (confounded,
//      and VGPR was 68-84 pre-fast_bases8).
// ---------------------------------------------------------------------------

typedef __bf16 bf16x8_t __attribute__((ext_vector_type(8)));
typedef float f32x4_t __attribute__((ext_vector_type(4)));

__device__ __forceinline__ float bf2f(unsigned short u) {
    union { float f; uint32_t i; } c; c.i = ((uint32_t)u) << 16; return c.f;
}
__device__ __forceinline__ unsigned short f2bf(float f) {
    union { float f; uint32_t u; } c; c.f = f;
    uint32_t u = c.u;
    u += 0x7FFFu + ((u >> 16) & 1u);   // round-to-nearest-even
    return (unsigned short)(u >> 16);
}
__device__ __forceinline__ bool f32world(const void* gridp) {
    return ((*(const unsigned int*)gridp) & 0xFFFFu) == 0xCCCDu;
}

// load knots (world-dependent) + uniform-grid inverse denominators
__device__ __forceinline__ void load_knots(const void* gridp, float* t, float* rr) {
    if (f32world(gridp)) {
        const float* g = (const float*)gridp;
#pragma unroll
        for (int k = 0; k < 12; ++k) t[k] = g[k];
    } else {
        const unsigned short* g = (const unsigned short*)gridp;
#pragma unroll
        for (int k = 0; k < 12; ++k) t[k] = bf2f(g[k]);
    }
    rr[0] = 1.0f / (t[1] - t[0]);
    rr[1] = 1.0f / (t[2] - t[0]);
    rr[2] = 1.0f / (t[3] - t[0]);
}

// Fast uniform-grid bases: only 4 of 8 cubic bases are nonzero at any x.
// span i = floor((x-t0)/h) (valid 0..10), u = frac; basis j nonzero iff
// d = i-j in {0..3} with the standard uniform cubic polys.  C2-continuous
// at span edges; i outside [0,10] -> all zero.  ~90 lane-ops vs ~240 for
// Cox-de-Boor.  Numerically verified R16-R21 (absmax unchanged). [R16/R18]
__device__ __forceinline__ int4 fast_bases8(float x, float t0, float invh) {
    float y  = (x - t0) * invh;
    float fi = floorf(y);
    int   i  = (int)fi;
    float u  = y - fi;
    float u2 = u * u, u3 = u2 * u;
    float um = 1.0f - u;
    const float c6 = 1.0f / 6.0f;
    float p0 = u3 * c6;                                  // d=0 (j=i)
    float p1 = (-3.f*u3 + 3.f*u2 + 3.f*u + 1.f) * c6;    // d=1
    float p2 = (3.f*u3 - 6.f*u2 + 4.f) * c6;             // d=2
    float p3 = um * um * um * c6;                        // d=3 (j=i-3)
    bool valid = (i >= 0) && (i <= 10);
    union { int4 v; unsigned short h[8]; } r;
#pragma unroll
    for (int g = 0; g < 8; ++g) {
        int d = i - g;
        float val = (d == 0) ? p0 : (d == 1) ? p1 : (d == 2) ? p2
                  : (d == 3) ? p3 : 0.0f;
        r.h[g] = f2bf(valid ? val : 0.0f);
    }
    return r.v;
}

// --------------------- merged weight f32->bf16 (or copy) -------------------
__global__ __launch_bounds__(256)
void cvt4_kernel(const void* __restrict__ s0, const void* __restrict__ s1,
                 const void* __restrict__ s2, const void* __restrict__ s3,
                 unsigned short* __restrict__ dst, const void* __restrict__ gridp)
{
    const int n0 = 262144;            // 2048*512/4
    const int n01 = n0 + 2097152;     // + 2048*512*8/4
    const int n012 = n01 + 262144;    // + 512*2048/4
    const int n = n012 + 2097152;     // + 512*2048*8/4
    int i = blockIdx.x * 256 + threadIdx.x;
    if (i >= n) return;
    const void* src; long off;
    if      (i < n0)   { src = s0; off = i; }
    else if (i < n01)  { src = s1; off = i - n0; }
    else if (i < n012) { src = s2; off = i - n01; }
    else               { src = s3; off = i - n012; }
    if (f32world(gridp)) {
        float4 v = ((const float4*)src)[off];
        ushort4 o;
        o.x = f2bf(v.x); o.y = f2bf(v.y); o.z = f2bf(v.z); o.w = f2bf(v.w);
        ((ushort4*)dst)[i] = o;
    } else {
        ((ushort4*)dst)[i] = ((const ushort4*)src)[off];
    }
}

// --------------------------- activations: silu + 8 bases -------------------
// XMODE: 0 = raw input (world f32/bf16), 1 = ws bf16.
// zbuf!=null: also zero zn4 float4s (folds the C2 memset into this dispatch).
template<int XMODE>
__global__ __launch_bounds__(256)
void act_kernel(const void* __restrict__ Xv, const void* __restrict__ gridp,
                unsigned short* __restrict__ S, unsigned short* __restrict__ BS,
                int total4, float* __restrict__ zbuf, int zn4)
{
    int gi = blockIdx.x * 256 + threadIdx.x;
    if (gi >= total4) return;

    if (zbuf && gi < zn4) ((float4*)zbuf)[gi] = (float4){0.f, 0.f, 0.f, 0.f};

    const bool w32 = f32world(gridp);
    float t[12], rr[3];
    load_knots(gridp, t, rr);

    float xv[4];
    if (XMODE == 0 && w32) {
        float4 v = ((const float4*)Xv)[gi];
        xv[0] = v.x; xv[1] = v.y; xv[2] = v.z; xv[3] = v.w;
    } else {
        ushort4 v = ((const ushort4*)Xv)[gi];
        xv[0] = bf2f(v.x); xv[1] = bf2f(v.y); xv[2] = bf2f(v.z); xv[3] = bf2f(v.w);
    }

    ushort4 sOut;
    unsigned short* sp = (unsigned short*)&sOut;
    int4 bsOut[4];

#pragma unroll
    for (int e = 0; e < 4; ++e) {
        float x = xv[e];
        float sg = 1.0f / (1.0f + __expf(-x));
        sp[e] = f2bf(x * sg);
        bsOut[e] = fast_bases8(x, t[0], rr[0]);           // [R18]
    }

    ((ushort4*)S)[gi] = sOut;
    int4* bp = (int4*)&BS[(long)gi * 32];
#pragma unroll
    for (int e = 0; e < 4; ++e) bp[e] = bsOut[e];
}

// ---------------- fused prep: weight-cvt + act1 + C2 zero [R22] ------------
// blocks [0, CVT_NB): weight conversion (4718592 ushort4 items).
// blocks [CVT_NB, CVT_NB+ACT_NB): act1 on x (f32/bf16 world) + zero C2.
__global__ __launch_bounds__(256)
void prep_kernel(const void* __restrict__ s0, const void* __restrict__ s1,
                 const void* __restrict__ s2, const void* __restrict__ s3,
                 unsigned short* __restrict__ dst,
                 const void* __restrict__ Xv,
                 unsigned short* __restrict__ S, unsigned short* __restrict__ BS,
                 float* __restrict__ zbuf,
                 const void* __restrict__ gridp)
{
    const int CVT_NB = 18432;         // 4718592 / 256
    const bool w32 = f32world(gridp);
    int b = blockIdx.x;

    if (b < CVT_NB) {
        const int n0 = 262144;            // 2048*512/4
        const int n01 = n0 + 2097152;     // + 2048*512*8/4
        const int n012 = n01 + 262144;    // + 512*2048/4
        int i = b * 256 + threadIdx.x;
        const void* src; long off;
        if      (i < n0)   { src = s0; off = i; }
        else if (i < n01)  { src = s1; off = i - n0; }
        else if (i < n012) { src = s2; off = i - n01; }
        else               { src = s3; off = i - n012; }
        if (w32) {
            float4 v = ((const float4*)src)[off];
            ushort4 o;
            o.x = f2bf(v.x); o.y = f2bf(v.y); o.z = f2bf(v.z); o.w = f2bf(v.w);
            ((ushort4*)dst)[i] = o;
        } else {
            ((ushort4*)dst)[i] = ((const ushort4*)src)[off];
        }
        return;
    }

    int gi = (b - CVT_NB) * 256 + threadIdx.x;   // < 524288 by grid construction

    ((float4*)zbuf)[gi] = (float4){0.f, 0.f, 0.f, 0.f};

    float t[12], rr[3];
    load_knots(gridp, t, rr);

    float xv[4];
    if (w32) {
        float4 v = ((const float4*)Xv)[gi];
        xv[0] = v.x; xv[1] = v.y; xv[2] = v.z; xv[3] = v.w;
    } else {
        ushort4 v = ((const ushort4*)Xv)[gi];
        xv[0] = bf2f(v.x); xv[1] = bf2f(v.y); xv[2] = bf2f(v.z); xv[3] = bf2f(v.w);
    }

    ushort4 sOut;
    unsigned short* sp = (unsigned short*)&sOut;
    int4 bsOut[4];
#pragma unroll
    for (int e = 0; e < 4; ++e) {
        float x = xv[e];
        float sg = 1.0f / (1.0f + __expf(-x));
        sp[e] = f2bf(x * sg);
        bsOut[e] = fast_bases8(x, t[0], rr[0]);
    }
    ((ushort4*)S)[gi] = sOut;
    int4* bp = (int4*)&BS[(long)gi * 32];
#pragma unroll
    for (int e = 0; e < 4; ++e) bp[e] = bsOut[e];
}

// --------------------------- two-segment MFMA bf16 GEMM --------------------
// Single-buffered LDS (R5/R19-confirmed winner). XOR-swizzled (0 conflicts).
// XCD-aware tile swizzle (R8). blockIdx.z selects K-tile range [kt0,kt1).
// OUT_MODE: 1 = f32 atomicAdd (split-K), 2 = final world-dependent store,
//           3 = fused layer-boundary epilogue (silu + fast_bases8). [R10/R18]
template<int BM, int BN, int OUT_MODE>
__global__ __launch_bounds__(256)
void gemm_seg(const unsigned short* __restrict__ A0, int K0,
              const unsigned short* __restrict__ A1, int K1,
              const unsigned short* __restrict__ B0,
              const unsigned short* __restrict__ B1,
              void* __restrict__ Cv, unsigned short* __restrict__ BSp,
              int N, int crow0, int ktiles,
              const void* __restrict__ gridp)
{
    constexpr int BK = 64;
    constexpr int TM = BM / 32;
    constexpr int TN = BN / 32;

    __shared__ unsigned short As[BM * BK];
    __shared__ unsigned short Bs[BN * BK];

    const int tid  = threadIdx.x;
    const int lane = tid & 63;
    const int w    = tid >> 6;
    const int wm   = w & 1;
    const int wn   = w >> 1;

    // ---- XCD-aware tile swizzle ----
    const int gx = gridDim.x, gy = gridDim.y, gz = gridDim.z;
    int bx = blockIdx.x, by = blockIdx.y, bz = blockIdx.z;
    {
        int NB = gx * gy * gz;
        if ((NB & 7) == 0) {
            int F = bx + gx * (by + gy * bz);      // launch order (x fastest)
            int T = (F & 7) * (NB >> 3) + (F >> 3); // XCD gets contiguous band
            int pl = gx * gy;
            bz = T / pl;
            int r = T - bz * pl;
            by = r / gx;
            bx = r - by * gx;
        }
    }

    const int rowA0 = by * BM;
    const int colC0 = bx * BN;

    const int nkt0 = K0 / BK;
    const int nkt  = nkt0 + K1 / BK;
    const int kt0  = bz * ktiles;
    const int kt1  = (kt0 + ktiles < nkt) ? kt0 + ktiles : nkt;

    // staging: lane covers (row = (w<<3)+(lane>>3), LDS slot = lane&7);
    // fetch global chunk (slot ^ (row&7)) so readers can de-swizzle.
    const int srow = (w << 3) + (lane >> 3);
    const int scol = (((lane & 7) ^ ((lane >> 3) & 7)) << 3);   // elements

    // fragment-read swizzled chunk offsets (elements), per ks
    const int q  = lane >> 4;       // 0..3
    const int l7 = lane & 7;        // == (fragment row) & 7
    const int cidx0 = ((q) ^ l7) << 3;
    const int cidx1 = ((4 + q) ^ l7) << 3;

    f32x4_t acc[TM][TN];
#pragma unroll
    for (int i = 0; i < TM; ++i)
#pragma unroll
        for (int j = 0; j < TN; ++j)
            acc[i][j] = (f32x4_t){0.f, 0.f, 0.f, 0.f};

    for (int kt = kt0; kt < kt1; ++kt) {
        const unsigned short* Abase;
        const unsigned short* Bbase;
        long ld; int ko;
        if (kt < nkt0) { Abase = A0; Bbase = B0; ld = K0; ko = kt * BK; }
        else           { Abase = A1; Bbase = B1; ld = K1; ko = (kt - nkt0) * BK; }

#pragma unroll
        for (int i = 0; i < BM / 32; ++i) {
            const unsigned short* g = Abase + (long)(rowA0 + i * 32 + srow) * ld + ko + scol;
            __builtin_amdgcn_global_load_lds(
                (const __attribute__((address_space(1))) void*)g,
                (__attribute__((address_space(3))) void*)&As[(i * 32 + (w << 3)) * BK],
                16, 0, 0);
        }
#pragma unroll
        for (int i = 0; i < BN / 32; ++i) {
            const unsigned short* g = Bbase + (long)(colC0 + i * 32 + srow) * ld + ko + scol;
            __builtin_amdgcn_global_load_lds(
                (const __attribute__((address_space(1))) void*)g,
                (__attribute__((address_space(3))) void*)&Bs[(i * 32 + (w << 3)) * BK],
                16, 0, 0);
        }
        __syncthreads();

#pragma unroll
        for (int ks = 0; ks < 2; ++ks) {
            const int cidx = ks ? cidx1 : cidx0;
            bf16x8_t af[TM], bfr[TN];
#pragma unroll
            for (int tm = 0; tm < TM; ++tm)
                af[tm] = *(const bf16x8_t*)&As[(wm * (BM / 2) + tm * 16 + (lane & 15)) * BK
                                               + cidx];
#pragma unroll
            for (int tn = 0; tn < TN; ++tn)
                bfr[tn] = *(const bf16x8_t*)&Bs[(wn * (BN / 2) + tn * 16 + (lane & 15)) * BK
                                                + cidx];
#pragma unroll
            for (int tm = 0; tm < TM; ++tm)
#pragma unroll
                for (int tn = 0; tn < TN; ++tn)
                    acc[tm][tn] = __builtin_amdgcn_mfma_f32_16x16x32_bf16(
                        af[tm], bfr[tn], acc[tm][tn], 0, 0, 0);
        }
        __syncthreads();
    }

    // C/D layout: col = lane&15, row = (lane>>4)*4 + reg  [m89-verified]
    const bool w32 = (OUT_MODE == 2) ? f32world(gridp) : false;
    float t[12], rr[3];
    if (OUT_MODE == 3) load_knots(gridp, t, rr);

#pragma unroll
    for (int tm = 0; tm < TM; ++tm) {
#pragma unroll
        for (int tn = 0; tn < TN; ++tn) {
            int row0 = crow0 + rowA0 + wm * (BM / 2) + tm * 16 + (lane >> 4) * 4;
            int col  = colC0 + wn * (BN / 2) + tn * 16 + (lane & 15);
#pragma unroll
            for (int r = 0; r < 4; ++r) {
                long off = (long)(row0 + r) * N + col;
                float v = acc[tm][tn][r];
                if (OUT_MODE == 1) {
                    unsafeAtomicAdd(&((float*)Cv)[off], v);
                } else if (OUT_MODE == 3) {
                    float sg = 1.0f / (1.0f + __expf(-v));
                    ((unsigned short*)Cv)[off] = f2bf(v * sg);
                    *(int4*)&BSp[off * 8] = fast_bases8(v, t[0], rr[0]);  // [R18]
                } else if (w32) {
                    ((float*)Cv)[off] = v;
                } else {
                    ((unsigned short*)Cv)[off] = f2bf(v);
                }
            }
        }
    }
}

// ------------------- f32 accumulator -> final output -----------------------
__global__ __launch_bounds__(256)
void accum_to_out(const float* __restrict__ acc, void* __restrict__ out,
                  int n4, const void* __restrict__ gridp)
{
    int i = blockIdx.x * 256 + threadIdx.x;
    if (i >= n4) return;
    float4 v = ((const float4*)acc)[i];
    if (f32world(gridp)) {
        ((float4*)out)[i] = v;
    } else {
        ushort4 o;
        o.x = f2bf(v.x); o.y = f2bf(v.y); o.z = f2bf(v.z); o.w = f2bf(v.w);
        ((ushort4*)out)[i] = o;
    }
}

// --------------------------- launcher --------------------------------------
extern "C" void kernel_launch(void* const* d_in, const int* in_sizes, int n_in,
                              void* d_out, int out_size, void* d_ws, size_t ws_size,
                              hipStream_t stream)
{
    const void* x   = d_in[0];
    const void* grd = d_in[1];
    const void* w1b = d_in[2];
    const void* w1s = d_in[3];
    const void* w2b = d_in[4];
    const void* w2s = d_in[5];

    const int NTOK = 4096, D1 = 512, D2 = 2048;
    const size_t MiB = 1024 * 1024;
    char* ws = (char*)d_ws;

    if (ws_size >= 224 * MiB) {
        // ------------------- fused path (R10/R18/R22) -------------------
        unsigned short* wcat   = (unsigned short*)ws;              // 36 MiB total
        unsigned short* w1b_bf = (unsigned short*)(ws);            //  2 MiB
        unsigned short* w1s_bf = (unsigned short*)(ws + 2  * MiB); // 16 MiB
        unsigned short* w2b_bf = (unsigned short*)(ws + 18 * MiB); //  2 MiB
        unsigned short* w2s_bf = (unsigned short*)(ws + 20 * MiB); // 16 MiB
        unsigned short* S1     = (unsigned short*)(ws + 36 * MiB); //  4 MiB
        unsigned short* BS1    = (unsigned short*)(ws + 40 * MiB); // 32 MiB
        unsigned short* S2     = (unsigned short*)(ws + 72 * MiB); // 16 MiB bf16 4096x2048
        unsigned short* BS2    = (unsigned short*)(ws + 88 * MiB); // 128 MiB (ends 216)
        float*          C2     = (float*)(ws + 216 * MiB);         //  8 MiB (ends 224)

        // R22a: fused prep = weight-cvt (18432 blocks) + act1/C2-zero (2048)
        prep_kernel<<<18432 + 2048, 256, 0, stream>>>(
            w1b, w1s, w2b, w2s, wcat, x, S1, BS1, (float*)C2, grd);

        // gemm1 (64x128, fused act2 epilogue) — R18 winner
        {
            dim3 g(D2 / 128, NTOK / 64, 1);
            gemm_seg<64, 128, 3><<<g, 256, 0, stream>>>(
                S1, D1, BS1, D1 * 8, w1b_bf, w1s_bf,
                (void*)S2, BS2, D2, 0, 72, grd);
        }

        // gemm2: R22b 64x128 split-K=8 -> grid (4,64,8)=2048 blocks,
        // LDS 24KB -> 6 blocks/CU. BN=128 keeps A-re-fetch x4 (no R21
        // fetch explosion); 16:6 MFMA:staging = proven gemm1 shape.
        {
            dim3 g(D1 / 128, NTOK / 64, 8);
            gemm_seg<64, 128, 1><<<g, 256, 0, stream>>>(
                S2, D2, BS2, D2 * 8, w2b_bf, w2s_bf,
                (void*)C2, nullptr, D1, 0, 36, grd);
        }

        accum_to_out<<<(NTOK * D1 / 4 + 255) / 256, 256, 0, stream>>>(
            C2, d_out, NTOK * D1 / 4, grd);
    } else {
        // ------------------- legacy small-ws path -------------------
        unsigned short* w1b_bf = (unsigned short*)(ws);
        unsigned short* w1s_bf = (unsigned short*)(ws + 2  * MiB);
        unsigned short* w2b_bf = (unsigned short*)(ws + 18 * MiB);
        unsigned short* w2s_bf = (unsigned short*)(ws + 20 * MiB);
        unsigned short* H      = (unsigned short*)(ws + 36 * MiB);
        unsigned short* S1     = (unsigned short*)(ws + 52 * MiB);
        unsigned short* BS1    = (unsigned short*)(ws + 56 * MiB);
        unsigned short* S2     = (unsigned short*)(ws + 52 * MiB);
        unsigned short* BS2    = (unsigned short*)(ws + 68 * MiB);

        int CT;
        if      (ws_size >= 100 * MiB) CT = 1024;
        else                           CT = 256;

        cvt4_kernel<<<(4718592 + 255) / 256, 256, 0, stream>>>(
            w1b, w1s, w2b, w2s, (unsigned short*)ws, grd);

        {
            act_kernel<0><<<(NTOK * D1 / 4 + 255) / 256, 256, 0, stream>>>(
                x, grd, S1, BS1, NTOK * D1 / 4, nullptr, 0);
            dim3 g(D2 / 128, NTOK / 128, 1);
            gemm_seg<128, 128, 2><<<g, 256, 0, stream>>>(
                S1, D1, BS1, D1 * 8, w1b_bf, w1s_bf, (void*)H, nullptr,
                D2, 0, 72, grd);
        }
        int nch = NTOK / CT;
        for (int c = 0; c < nch; ++c) {
            long tokOff = (long)c * CT;
            act_kernel<1><<<(CT * D2 / 4 + 255) / 256, 256, 0, stream>>>(
                (const void*)(H + tokOff * D2), grd, S2 + tokOff * D2, BS2,
                CT * D2 / 4, nullptr, 0);
            dim3 g(D1 / 128, CT / 64, 1);
            gemm_seg<64, 128, 2><<<g, 256, 0, stream>>>(
                S2 + tokOff * D2, D2, BS2, D2 * 8, w2b_bf, w2s_bf,
                d_out, nullptr, D1, (int)tokOff, 288, grd);
        }
    }
}